// Round 9
// baseline (226.362 us; speedup 1.0000x reference)
//
#include <hip/hip_runtime.h>
#include <stdint.h>

#define B_ 32
#define D_ 512
#define P_ 1024   // H*W
#define N_ 32768  // B*P
#define K_ 1024

// 1-segment (bf16-hi only) distance error: sigma ~0.07/dist, gap sigma ~0.1.
// 0.75 = 7.5 sigma guard; measured flag rate ~3-5% of tokens -> fp64 repair.
#define GAP_THR 0.75f

typedef unsigned long long u64;
typedef __attribute__((ext_vector_type(8))) short short8;
typedef __attribute__((ext_vector_type(4))) float float4v;

__device__ __forceinline__ unsigned fkey(float f) {
    unsigned u = __float_as_uint(f);
    return (u & 0x80000000u) ? ~u : (u | 0x80000000u);
}
__device__ __forceinline__ float funkey(unsigned k) {
    unsigned u = (k & 0x80000000u) ? (k & 0x7fffffffu) : ~k;
    return __uint_as_float(u);
}
__device__ __forceinline__ unsigned short f2bf(float x) {
    unsigned u = __float_as_uint(x);
    unsigned r = (u + 0x7fffu + ((u >> 16) & 1u)) >> 16;
    return (unsigned short)r;
}
__device__ __forceinline__ float bf2f(unsigned short h) {
    return __uint_as_float(((unsigned)h) << 16);
}

#define GLOAD_LDS16(gsrc, ldst) \
    __builtin_amdgcn_global_load_lds((const __attribute__((address_space(1))) unsigned int*)(const void*)(gsrc), \
                                     (__attribute__((address_space(3))) unsigned int*)(void*)(ldst), 16, 0, 0)

// ------------------------------------------------------------- k_prep
// blocks 0..255: z [32,512,1024] fp32 -> Xhi bf16 [32768][512] (LDS transpose)
// blocks 256..383: emb -> Ehi bf16 + ET fp32 [512][1024] + enorm(f32)/enormD(f64);
//                  zero counts/flagCount
// Zl uses d-column XOR key (p&7)<<2 so the transpose read is 2x ds_read_b128.
__global__ __launch_bounds__(256) void k_prep(const float* __restrict__ z,
                                              unsigned short* __restrict__ Xhi,
                                              const float* __restrict__ emb,
                                              unsigned short* __restrict__ Ehi,
                                              float* __restrict__ ET,
                                              float* __restrict__ enorm,
                                              double* __restrict__ enormD,
                                              int* __restrict__ counts,
                                              int* __restrict__ flagCount) {
    __shared__ __align__(16) float Zl[128][68];   // 34.8 KB; prepE aliases [8][513]
    int tid = threadIdx.x;

    if (blockIdx.x >= 256) {
        // ---- prepE: 128 blocks x 8 codes (wave w handles 2 codes)
        int base = (blockIdx.x - 256) * 8;
        if (tid < 8) counts[base + tid] = 0;
        if (blockIdx.x == 256 && tid == 0) *flagCount = 0;
        int wave = tid >> 6, lane = tid & 63;
        float* Es = &Zl[0][0];      // [8][513]
        #pragma unroll
        for (int cc = 0; cc < 2; ++cc) {
            int ci = wave * 2 + cc;
            int c = base + ci;
            const float4* row = (const float4*)(emb + (size_t)c * D_);
            float4 a = row[lane * 2];
            float4 b2 = row[lane * 2 + 1];
            float xs[8] = {a.x, a.y, a.z, a.w, b2.x, b2.y, b2.z, b2.w};
            unsigned short h[8];
            double s = 0.0;
            #pragma unroll
            for (int j = 0; j < 8; ++j) {
                h[j] = f2bf(xs[j]);
                Es[ci * 513 + lane * 8 + j] = xs[j];
                double d = (double)xs[j];
                s += d * d;
            }
            uint4 w;
            w.x = (unsigned)h[0] | ((unsigned)h[1] << 16);
            w.y = (unsigned)h[2] | ((unsigned)h[3] << 16);
            w.z = (unsigned)h[4] | ((unsigned)h[5] << 16);
            w.w = (unsigned)h[6] | ((unsigned)h[7] << 16);
            *(uint4*)(Ehi + (size_t)c * D_ + lane * 8) = w;
            #pragma unroll
            for (int off = 32; off; off >>= 1) s += __shfl_down(s, off, 64);
            if (lane == 0) { enorm[c] = (float)s; enormD[c] = s; }
        }
        __syncthreads();
        // transpose write: thread handles d = tid, tid+256 -> ET[d][base..base+7]
        #pragma unroll
        for (int g = 0; g < 2; ++g) {
            int d = g * 256 + tid;
            float v[8];
            #pragma unroll
            for (int cc = 0; cc < 8; ++cc) v[cc] = Es[cc * 513 + d];
            float4* dst = (float4*)(ET + (size_t)d * 1024 + base);
            dst[0] = make_float4(v[0], v[1], v[2], v[3]);
            dst[1] = make_float4(v[4], v[5], v[6], v[7]);
        }
        return;
    }

    // ---- prep: 128 tokens x 512 dims per block
    int b = blockIdx.x >> 3, pt = blockIdx.x & 7;
    int p0 = pt * 128;
    int t0 = b * P_ + p0;
    const float* zb = z + ((size_t)b * D_) * P_ + p0;
    int c8 = tid & 7, pp = tid >> 3;
    int rkey = (pp & 7) << 2;   // reader key: p&7 == pp&7 (g*32 doesn't change low bits)

    for (int dc = 0; dc < 8; ++dc) {
        int d0 = dc * 64;
        __syncthreads();
        #pragma unroll
        for (int jj = 0; jj < 8; ++jj) {
            int flat = jj * 256 + tid;
            int d = flat >> 5, p4 = flat & 31;
            float4 v = *(const float4*)(zb + (size_t)(d0 + d) * P_ + p4 * 4);
            int p_ = p4 * 4;
            Zl[p_ + 0][d ^ (((p_ + 0) & 7) << 2)] = v.x;
            Zl[p_ + 1][d ^ (((p_ + 1) & 7) << 2)] = v.y;
            Zl[p_ + 2][d ^ (((p_ + 2) & 7) << 2)] = v.z;
            Zl[p_ + 3][d ^ (((p_ + 3) & 7) << 2)] = v.w;
        }
        __syncthreads();
        #pragma unroll
        for (int g = 0; g < 4; ++g) {
            int p = pp + g * 32;
            float4 va = *(const float4*)&Zl[p][(c8 * 8) ^ rkey];
            float4 vb = *(const float4*)&Zl[p][(c8 * 8 + 4) ^ rkey];
            unsigned short hh[8];
            hh[0] = f2bf(va.x); hh[1] = f2bf(va.y);
            hh[2] = f2bf(va.z); hh[3] = f2bf(va.w);
            hh[4] = f2bf(vb.x); hh[5] = f2bf(vb.y);
            hh[6] = f2bf(vb.z); hh[7] = f2bf(vb.w);
            uint4 w;
            w.x = (unsigned)hh[0] | ((unsigned)hh[1] << 16);
            w.y = (unsigned)hh[2] | ((unsigned)hh[3] << 16);
            w.z = (unsigned)hh[4] | ((unsigned)hh[5] << 16);
            w.w = (unsigned)hh[6] | ((unsigned)hh[7] << 16);
            *(uint4*)(Xhi + (size_t)(t0 + p) * D_ + d0 + c8 * 8) = w;
        }
    }
}

// ------------------------------------------------------------- k_gemm
// 256x256 tile, BK=64, 8 waves, 8-phase schedule, counted vmcnt, setprio.
// A = codes (Ehi), B = tokens (Xhi). K' = 512 = 8 tiles.
__global__ __launch_bounds__(512, 2) void k_gemm(const unsigned short* __restrict__ Xhi,
                                                 const unsigned short* __restrict__ Ehi,
                                                 const float* __restrict__ enorm,
                                                 u64* __restrict__ part) {
    __shared__ __align__(16) char smem[131072];
    const int tid = threadIdx.x;
    const int wave = tid >> 6, lane = tid & 63;
    const int lr = lane & 15, lg = lane >> 4;
    const int wr = wave >> 2, wc = wave & 3;
    const int work = (blockIdx.x & 7) * 64 + (blockIdx.x >> 3);
    const int rb = work >> 2, cb = work & 3;
    const int t0 = rb * 256, c0 = cb * 256;

    float4v acc[8][4];
    #pragma unroll
    for (int i = 0; i < 8; ++i)
        #pragma unroll
        for (int j = 0; j < 4; ++j)
            acc[i][j] = (float4v){0.f, 0.f, 0.f, 0.f};

    // half-tile h: tile T=h>>2, j=h&3 (0=A-k0, 1=B-k0, 2=A-k1, 3=B-k1)
    auto stageHalf = [&](int h) {
        if (h >= 32) return;
        int T = h >> 2, j = h & 3;
        int khalf = j >> 1, isB = j & 1;
        const unsigned short* plane = isB ? Xhi : Ehi;
        int row0 = isB ? t0 : c0;
        int kseg = T * 64 + khalf * 32;
        char* region = smem + (T & 1) * 65536 + isB * 32768 + khalf * 16384;
        #pragma unroll
        for (int jj = 0; jj < 2; ++jj) {
            int o = jj * 8192 + wave * 1024 + lane * 16;
            int pair = o >> 7;
            int sl = ((o >> 4) & 7) ^ (pair & 7);
            int row = pair * 2 + (sl >> 2);
            int k8 = sl & 3;
            GLOAD_LDS16(plane + (size_t)(row0 + row) * D_ + kseg + k8 * 8,
                        region + jj * 8192 + wave * 1024);
        }
    };

    for (int h = 0; h < 6; ++h) stageHalf(h);

    for (int t = 0; t < 8; ++t) {
        const int buf = t & 1;
        const char* Ab = smem + buf * 65536;
        const char* Bb = smem + buf * 65536 + 32768;
        if (t < 7) { asm volatile("s_waitcnt vmcnt(4)" ::: "memory"); }
        else       { asm volatile("s_waitcnt vmcnt(0)" ::: "memory"); }
        __builtin_amdgcn_s_barrier();
        __builtin_amdgcn_sched_barrier(0);
        #pragma unroll
        for (int q = 0; q < 4; ++q) {
            const int ks = q >> 1, mq = q & 1;
            const char* Ar = Ab + ks * 16384;
            const char* Br = Bb + ks * 16384;
            short8 af[4], bf[4];
            #pragma unroll
            for (int i = 0; i < 4; ++i) {
                int arow = wr * 128 + (mq * 4 + i) * 16 + lr;
                int ap = arow >> 1;
                int as_ = (((arow & 1) << 2) | lg) ^ (ap & 7);
                af[i] = *(const short8*)(Ar + ap * 128 + as_ * 16);
            }
            #pragma unroll
            for (int i = 0; i < 4; ++i) {
                int brow = wc * 64 + i * 16 + lr;
                int bp = brow >> 1;
                int bs_ = (((brow & 1) << 2) | lg) ^ (bp & 7);
                bf[i] = *(const short8*)(Br + bp * 128 + bs_ * 16);
            }
            stageHalf(4 * t + q + 6);
            __builtin_amdgcn_sched_barrier(0);
            __builtin_amdgcn_s_barrier();
            asm volatile("s_waitcnt lgkmcnt(0)" ::: "memory");
            __builtin_amdgcn_sched_barrier(0);
            __builtin_amdgcn_s_setprio(1);
            #pragma unroll
            for (int i = 0; i < 4; ++i)
                #pragma unroll
                for (int j = 0; j < 4; ++j)
                    acc[mq * 4 + i][j] = __builtin_amdgcn_mfma_f32_16x16x32_bf16(af[i], bf[j], acc[mq * 4 + i][j], 0, 0, 0);
            __builtin_amdgcn_s_setprio(0);
            __builtin_amdgcn_s_barrier();
        }
    }

    float en[8][4];
    #pragma unroll
    for (int mi = 0; mi < 8; ++mi)
        #pragma unroll
        for (int rr = 0; rr < 4; ++rr)
            en[mi][rr] = enorm[c0 + wr * 128 + mi * 16 + lg * 4 + rr];

    #pragma unroll
    for (int ni = 0; ni < 4; ++ni) {
        float v1 = 3.4e38f, v2 = 3.4e38f;
        int c1 = 0;
        #pragma unroll
        for (int mi = 0; mi < 8; ++mi) {
            #pragma unroll
            for (int rr = 0; rr < 4; ++rr) {
                float dist = fmaf(-2.f, acc[mi][ni][rr], en[mi][rr]);
                int code = c0 + wr * 128 + mi * 16 + lg * 4 + rr;
                if (dist < v1) { v2 = v1; v1 = dist; c1 = code; }
                else v2 = fminf(v2, dist);
            }
        }
        #pragma unroll
        for (int mask = 16; mask <= 32; mask <<= 1) {
            float ov1 = __shfl_xor(v1, mask, 64);
            int   oc1 = __shfl_xor(c1, mask, 64);
            float ov2 = __shfl_xor(v2, mask, 64);
            bool take = (ov1 < v1) || (ov1 == v1 && oc1 < c1);
            float loser = take ? v1 : ov1;
            v2 = fminf(fminf(v2, ov2), loser);
            if (take) { v1 = ov1; c1 = oc1; }
        }
        if (lg == 0) {
            int t = t0 + wc * 64 + ni * 16 + lr;
            ulonglong2 pk;
            pk.x = ((u64)fkey(v1) << 32) | (unsigned)c1;
            pk.y = ((u64)fkey(v2) << 32);
            *(ulonglong2*)&part[((size_t)t * 8 + cb * 2 + wr) * 2] = pk;
        }
    }
}

// ------------------------------------------------------------- k_merge
__global__ __launch_bounds__(256) void k_merge(const u64* __restrict__ part,
                                               int* __restrict__ indices,
                                               int* __restrict__ flags,
                                               int* __restrict__ flagCount) {
    int t = blockIdx.x * 256 + threadIdx.x;
    ulonglong2 a0 = *(const ulonglong2*)&part[(size_t)t * 16];
    u64 m1 = a0.x;
    float m2v = funkey((unsigned)(a0.y >> 32));
    for (int s = 1; s < 8; ++s) {
        ulonglong2 a = *(const ulonglong2*)&part[((size_t)t * 8 + s) * 2];
        float ax = funkey((unsigned)(a.x >> 32));
        float ay = funkey((unsigned)(a.y >> 32));
        if (a.x < m1) { m2v = fminf(m2v, funkey((unsigned)(m1 >> 32))); m1 = a.x; }
        else m2v = fminf(m2v, ax);
        m2v = fminf(m2v, ay);
    }
    indices[t] = (int)(m1 & 0xffffffffu);
    float v1 = funkey((unsigned)(m1 >> 32));
    if (m2v - v1 < GAP_THR) {
        int pos = atomicAdd(flagCount, 1);
        if (pos < N_) flags[pos] = t;
    }
}

// ------------------------------------------------------------- k_repair
// fp64 exact re-argmin for flagged tokens. Lane-per-code with transposed
// codebook ET[512][1024]; 4 tokens per block amortize ET traffic.
__global__ __launch_bounds__(256) void k_repair(const float* __restrict__ z,
                                                const float* __restrict__ ET,
                                                const double* __restrict__ enormD,
                                                const int* __restrict__ flags,
                                                const int* __restrict__ flagCount,
                                                int* __restrict__ indices) {
    __shared__ double zl[4][512];   // 16 KB
    __shared__ double rv[256];
    __shared__ int rc[256];
    const int tid = threadIdx.x;
    int nf = *flagCount;
    if (nf > N_) nf = N_;
    int nb = (nf + 3) >> 2;
    for (int bi = blockIdx.x; bi < nb; bi += gridDim.x) {
        int base = bi * 4;
        int ntok = nf - base; if (ntok > 4) ntok = 4;
        __syncthreads();   // protect zl reuse across grid-stride iterations
        for (int i = tid; i < 2048; i += 256) {
            int g = i >> 9, d = i & 511;
            if (g < ntok) {
                int t = flags[base + g];
                zl[g][d] = (double)z[(size_t)(t >> 10) * (D_ * P_) + (size_t)d * P_ + (t & 1023)];
            } else {
                zl[g][d] = 0.0;
            }
        }
        __syncthreads();

        double acc[4][4];
        #pragma unroll
        for (int g = 0; g < 4; ++g)
            #pragma unroll
            for (int k = 0; k < 4; ++k) acc[g][k] = 0.0;

        #pragma unroll 4
        for (int d = 0; d < 512; ++d) {
            const float* ep = ET + (size_t)d * 1024 + tid;
            double e0 = (double)ep[0];
            double e1 = (double)ep[256];
            double e2 = (double)ep[512];
            double e3 = (double)ep[768];
            double z0 = zl[0][d], z1 = zl[1][d], z2 = zl[2][d], z3 = zl[3][d];
            acc[0][0] = fma(e0, z0, acc[0][0]);
            acc[0][1] = fma(e1, z0, acc[0][1]);
            acc[0][2] = fma(e2, z0, acc[0][2]);
            acc[0][3] = fma(e3, z0, acc[0][3]);
            acc[1][0] = fma(e0, z1, acc[1][0]);
            acc[1][1] = fma(e1, z1, acc[1][1]);
            acc[1][2] = fma(e2, z1, acc[1][2]);
            acc[1][3] = fma(e3, z1, acc[1][3]);
            acc[2][0] = fma(e0, z2, acc[2][0]);
            acc[2][1] = fma(e1, z2, acc[2][1]);
            acc[2][2] = fma(e2, z2, acc[2][2]);
            acc[2][3] = fma(e3, z2, acc[2][3]);
            acc[3][0] = fma(e0, z3, acc[3][0]);
            acc[3][1] = fma(e1, z3, acc[3][1]);
            acc[3][2] = fma(e2, z3, acc[3][2]);
            acc[3][3] = fma(e3, z3, acc[3][3]);
        }

        for (int g = 0; g < ntok; ++g) {
            double bv = 1e300;
            int bc = 0;
            #pragma unroll
            for (int k = 0; k < 4; ++k) {
                int c = k * 256 + tid;   // ascending c: strict < keeps lowest on tie
                double dist = enormD[c] - 2.0 * acc[g][k];
                if (dist < bv) { bv = dist; bc = c; }
            }
            rv[tid] = bv; rc[tid] = bc;
            __syncthreads();
            for (int st = 128; st; st >>= 1) {
                if (tid < st) {
                    if (rv[tid + st] < rv[tid] ||
                        (rv[tid + st] == rv[tid] && rc[tid + st] < rc[tid])) {
                        rv[tid] = rv[tid + st]; rc[tid] = rc[tid + st];
                    }
                }
                __syncthreads();
            }
            if (tid == 0) indices[flags[base + g]] = rc[0];
            __syncthreads();
        }
    }
}

// ------------------------------------------------------------- k_out
// blocks 0..4095: one-hot encodings + counts (coalesced streaming writes).
// blocks 4096..4607: z_q gather, 512 blocks x 64 tokens x 512 dims.
// emb rows staged d-major in LDS El[64][68] with XOR key ((d>>3)&7)<<2 on the
// token column: stage writes are 2-way/bank (free), main-loop reads are one
// ds_read_b128 per thread (replaces r8's 8-way-conflicted scalar reads).
__global__ __launch_bounds__(256) void k_out(const int* __restrict__ indices,
                                             float* __restrict__ enc,
                                             int* __restrict__ counts,
                                             const float* __restrict__ z,
                                             const float* __restrict__ emb,
                                             float* __restrict__ zq,
                                             float* __restrict__ lossp) {
    int tid = threadIdx.x;
    if (blockIdx.x < 4096) {
        int r = blockIdx.x * 8 + (tid >> 5);
        int l = tid & 31;
        int idx = indices[r];
        if (l == 0) atomicAdd(&counts[idx], 1);
        float4* rowp = (float4*)(enc + (size_t)r * K_);
        #pragma unroll
        for (int i = 0; i < 8; ++i) {
            int c4 = i * 32 + l;
            int base = c4 * 4;
            float4 v;
            v.x = (idx == base) ? 1.f : 0.f;
            v.y = (idx == base + 1) ? 1.f : 0.f;
            v.z = (idx == base + 2) ? 1.f : 0.f;
            v.w = (idx == base + 3) ? 1.f : 0.f;
            rowp[c4] = v;
        }
        return;
    }

    // ---- gather half: 512 blocks, each 64 tokens x 512 dims
    __shared__ int sIdx[64];
    __shared__ __align__(16) float El[64][68];   // [dim-in-chunk][token^key]
    int gb = blockIdx.x - 4096;
    int b = gb >> 4, pt = gb & 15;
    int p0 = pt * 64;
    if (tid < 64) sIdx[tid] = indices[b * P_ + p0 + tid];
    __syncthreads();

    float lsum = 0.f;
    for (int dc = 0; dc < 8; ++dc) {
        int d0 = dc * 64;
        // stage emb rows: 2 passes x 32 tokens; 8 lanes x 32B per token row
        #pragma unroll
        for (int pass = 0; pass < 2; ++pass) {
            int p = pass * 32 + (tid >> 3);
            int l8 = tid & 7;
            const float* er = emb + (size_t)sIdx[p] * D_ + d0 + l8 * 8;
            float4 e0 = *(const float4*)er;
            float4 e1 = *(const float4*)(er + 4);
            int px = p ^ (l8 << 2);       // key = ((d>>3)&7)<<2, d = l8*8+j
            int dr = l8 * 8;
            El[dr + 0][px] = e0.x; El[dr + 1][px] = e0.y;
            El[dr + 2][px] = e0.z; El[dr + 3][px] = e0.w;
            El[dr + 4][px] = e1.x; El[dr + 5][px] = e1.y;
            El[dr + 6][px] = e1.z; El[dr + 7][px] = e1.w;
        }
        __syncthreads();
        #pragma unroll
        for (int it = 0; it < 4; ++it) {
            int f = it * 256 + tid;
            int d = f >> 4, p4 = f & 15;
            size_t zoff = (size_t)b * (D_ * P_) + (size_t)(d0 + d) * P_ + p0 + p4 * 4;
            float4 zv = *(const float4*)(z + zoff);
            int key = ((d >> 3) & 7) << 2;
            float4 ev = *(const float4*)&El[d][(p4 * 4) ^ key];
            float q0 = ev.x - zv.x, q1 = ev.y - zv.y;
            float q2 = ev.z - zv.z, q3 = ev.w - zv.w;
            float4 o;
            o.x = zv.x + q0; o.y = zv.y + q1; o.z = zv.z + q2; o.w = zv.w + q3;
            *(float4*)(zq + zoff) = o;
            lsum += q0 * q0 + q1 * q1 + q2 * q2 + q3 * q3;
        }
        __syncthreads();
    }
    #pragma unroll
    for (int off = 32; off; off >>= 1) lsum += __shfl_down(lsum, off, 64);
    __shared__ float wsum[4];
    if ((tid & 63) == 0) wsum[tid >> 6] = lsum;
    __syncthreads();
    if (tid == 0) lossp[gb] = wsum[0] + wsum[1] + wsum[2] + wsum[3];
}

// ------------------------------------------------------------- k_final
__global__ __launch_bounds__(1024) void k_final(const float* __restrict__ lossp,
                                                const int* __restrict__ counts,
                                                float* __restrict__ out_loss,
                                                float* __restrict__ out_perp) {
    int tid = threadIdx.x;
    float s = (tid < 512) ? lossp[tid] : 0.f;
    #pragma unroll
    for (int off = 32; off; off >>= 1) s += __shfl_down(s, off, 64);
    __shared__ float red[16];
    if ((tid & 63) == 0) red[tid >> 6] = s;

    float pr = (float)counts[tid] * (1.f / 32768.f);
    float term = pr * logf(pr + 1e-10f);
    #pragma unroll
    for (int off = 32; off; off >>= 1) term += __shfl_down(term, off, 64);
    __shared__ float red2[16];
    if ((tid & 63) == 0) red2[tid >> 6] = term;
    __syncthreads();
    if (tid == 0) {
        float tot = 0.f;
        for (int i = 0; i < 16; ++i) tot += red[i];
        *out_loss = 0.25f * (tot / 16777216.f);
        float t2 = 0.f;
        for (int i = 0; i < 16; ++i) t2 += red2[i];
        *out_perp = expf(-t2);
    }
}

// ------------------------------------------------------------- launch
extern "C" void kernel_launch(void* const* d_in, const int* in_sizes, int n_in,
                              void* d_out, int out_size, void* d_ws, size_t ws_size,
                              hipStream_t stream) {
    const float* z   = (const float*)d_in[0];   // [32,512,32,32]
    const float* emb = (const float*)d_in[1];   // [1024,512]

    float* zq       = (float*)d_out;            // 16777216
    float* out_loss = zq + 16777216;
    float* out_perp = zq + 16777217;
    float* enc      = zq + 16777218;            // 33554432 floats

    char* ws = (char*)d_ws;
    float* enorm   = (float*)ws;                          // 4 KB
    int* counts    = (int*)(ws + 4096);                   // 4 KB
    int* flagCount = (int*)(ws + 8192);                   // 4 B
    double* enormD = (double*)(ws + 16384);               // 8 KB
    int* flags     = (int*)(ws + 24576);                  // 128 KB
    int* indices   = (int*)(ws + 24576 + 131072);         // 128 KB
    float* lossp   = (float*)(ws + 24576 + 262144);       // 2 KB used

    // big scratch carved from the enc region of d_out (fully consumed before
    // k_out overwrites it; rewritten every call -> deterministic).
    char* sb = (char*)d_out + 67108880;
    unsigned short* Xhi  = (unsigned short*)(sb);                   // 33.5 MB
    unsigned short* EhiP = (unsigned short*)(sb + 33554432);        // 1 MB
    u64* part = (u64*)(sb + 34603008);                              // 4 MB
    float* ET = (float*)(sb + 38797312);                            // 2 MB

    k_prep<<<384, 256, 0, stream>>>(z, Xhi, emb, EhiP, ET, enorm, enormD, counts, flagCount);
    k_gemm<<<512, 512, 0, stream>>>(Xhi, EhiP, enorm, part);
    k_merge<<<128, 256, 0, stream>>>(part, indices, flags, flagCount);
    k_repair<<<512, 256, 0, stream>>>(z, ET, enormD, flags, flagCount, indices);
    k_out<<<4608, 256, 0, stream>>>(indices, enc, counts, z, emb, zq, lossp);
    k_final<<<1, 1024, 0, stream>>>(lossp, counts, out_loss, out_perp);
}

// Round 10
// 216.624 us; speedup vs baseline: 1.0450x; 1.0450x over previous
//
#include <hip/hip_runtime.h>
#include <stdint.h>

#define B_ 32
#define D_ 512
#define P_ 1024   // H*W
#define N_ 32768  // B*P
#define K_ 1024

// 1-segment (bf16-hi only) distance error: sigma ~0.07/dist, gap sigma ~0.1.
// 0.75 = 7.5 sigma guard; measured flag rate ~3-5% of tokens -> fp64 repair.
#define GAP_THR 0.75f

typedef unsigned long long u64;
typedef __attribute__((ext_vector_type(8))) short short8;
typedef __attribute__((ext_vector_type(4))) float float4v;

__device__ __forceinline__ unsigned fkey(float f) {
    unsigned u = __float_as_uint(f);
    return (u & 0x80000000u) ? ~u : (u | 0x80000000u);
}
__device__ __forceinline__ float funkey(unsigned k) {
    unsigned u = (k & 0x80000000u) ? (k & 0x7fffffffu) : ~k;
    return __uint_as_float(u);
}
__device__ __forceinline__ unsigned short f2bf(float x) {
    unsigned u = __float_as_uint(x);
    unsigned r = (u + 0x7fffu + ((u >> 16) & 1u)) >> 16;
    return (unsigned short)r;
}
__device__ __forceinline__ float bf2f(unsigned short h) {
    return __uint_as_float(((unsigned)h) << 16);
}

#define GLOAD_LDS16(gsrc, ldst) \
    __builtin_amdgcn_global_load_lds((const __attribute__((address_space(1))) unsigned int*)(const void*)(gsrc), \
                                     (__attribute__((address_space(3))) unsigned int*)(void*)(ldst), 16, 0, 0)

// ------------------------------------------------------------- k_prep
// (r8-exact; r9's LDS swizzle regressed -- HBM-bound regime, LDS not critical)
// blocks 0..255: z [32,512,1024] fp32 -> Xhi bf16 [32768][512] (LDS transpose)
// blocks 256..383: emb -> Ehi bf16 + ET fp32 [512][1024] + enorm(f32)/enormD(f64);
//                  zero counts/flagCount
__global__ __launch_bounds__(256) void k_prep(const float* __restrict__ z,
                                              unsigned short* __restrict__ Xhi,
                                              const float* __restrict__ emb,
                                              unsigned short* __restrict__ Ehi,
                                              float* __restrict__ ET,
                                              float* __restrict__ enorm,
                                              double* __restrict__ enormD,
                                              int* __restrict__ counts,
                                              int* __restrict__ flagCount) {
    __shared__ float Zl[128][67];   // 34.3 KB; prepE aliases first 8*513 floats
    int tid = threadIdx.x;

    if (blockIdx.x >= 256) {
        // ---- prepE: 128 blocks x 8 codes (wave w handles 2 codes)
        int base = (blockIdx.x - 256) * 8;
        if (tid < 8) counts[base + tid] = 0;
        if (blockIdx.x == 256 && tid == 0) *flagCount = 0;
        int wave = tid >> 6, lane = tid & 63;
        float* Es = &Zl[0][0];      // [8][513]
        #pragma unroll
        for (int cc = 0; cc < 2; ++cc) {
            int ci = wave * 2 + cc;
            int c = base + ci;
            const float4* row = (const float4*)(emb + (size_t)c * D_);
            float4 a = row[lane * 2];
            float4 b2 = row[lane * 2 + 1];
            float xs[8] = {a.x, a.y, a.z, a.w, b2.x, b2.y, b2.z, b2.w};
            unsigned short h[8];
            double s = 0.0;
            #pragma unroll
            for (int j = 0; j < 8; ++j) {
                h[j] = f2bf(xs[j]);
                Es[ci * 513 + lane * 8 + j] = xs[j];
                double d = (double)xs[j];
                s += d * d;
            }
            uint4 w;
            w.x = (unsigned)h[0] | ((unsigned)h[1] << 16);
            w.y = (unsigned)h[2] | ((unsigned)h[3] << 16);
            w.z = (unsigned)h[4] | ((unsigned)h[5] << 16);
            w.w = (unsigned)h[6] | ((unsigned)h[7] << 16);
            *(uint4*)(Ehi + (size_t)c * D_ + lane * 8) = w;
            #pragma unroll
            for (int off = 32; off; off >>= 1) s += __shfl_down(s, off, 64);
            if (lane == 0) { enorm[c] = (float)s; enormD[c] = s; }
        }
        __syncthreads();
        // transpose write: thread handles d = tid, tid+256 -> ET[d][base..base+7]
        #pragma unroll
        for (int g = 0; g < 2; ++g) {
            int d = g * 256 + tid;
            float v[8];
            #pragma unroll
            for (int cc = 0; cc < 8; ++cc) v[cc] = Es[cc * 513 + d];
            float4* dst = (float4*)(ET + (size_t)d * 1024 + base);
            dst[0] = make_float4(v[0], v[1], v[2], v[3]);
            dst[1] = make_float4(v[4], v[5], v[6], v[7]);
        }
        return;
    }

    // ---- prep: 128 tokens x 512 dims per block
    int b = blockIdx.x >> 3, pt = blockIdx.x & 7;
    int p0 = pt * 128;
    int t0 = b * P_ + p0;
    const float* zb = z + ((size_t)b * D_) * P_ + p0;
    int c8 = tid & 7, pp = tid >> 3;

    for (int dc = 0; dc < 8; ++dc) {
        int d0 = dc * 64;
        __syncthreads();
        #pragma unroll
        for (int jj = 0; jj < 8; ++jj) {
            int flat = jj * 256 + tid;
            int d = flat >> 5, p4 = flat & 31;
            float4 v = *(const float4*)(zb + (size_t)(d0 + d) * P_ + p4 * 4);
            Zl[p4 * 4 + 0][d] = v.x;
            Zl[p4 * 4 + 1][d] = v.y;
            Zl[p4 * 4 + 2][d] = v.z;
            Zl[p4 * 4 + 3][d] = v.w;
        }
        __syncthreads();
        #pragma unroll
        for (int g = 0; g < 4; ++g) {
            int p = pp + g * 32;
            unsigned short hh[8];
            #pragma unroll
            for (int j = 0; j < 8; ++j) hh[j] = f2bf(Zl[p][c8 * 8 + j]);
            uint4 w;
            w.x = (unsigned)hh[0] | ((unsigned)hh[1] << 16);
            w.y = (unsigned)hh[2] | ((unsigned)hh[3] << 16);
            w.z = (unsigned)hh[4] | ((unsigned)hh[5] << 16);
            w.w = (unsigned)hh[6] | ((unsigned)hh[7] << 16);
            *(uint4*)(Xhi + (size_t)(t0 + p) * D_ + d0 + c8 * 8) = w;
        }
    }
}

// ------------------------------------------------------------- k_gemm
// 256x256 tile, BK=64, 8 waves, 8-phase schedule, counted vmcnt, setprio.
// A = codes (Ehi), B = tokens (Xhi). K' = 512 = 8 tiles.
__global__ __launch_bounds__(512, 2) void k_gemm(const unsigned short* __restrict__ Xhi,
                                                 const unsigned short* __restrict__ Ehi,
                                                 const float* __restrict__ enorm,
                                                 u64* __restrict__ part) {
    __shared__ __align__(16) char smem[131072];
    const int tid = threadIdx.x;
    const int wave = tid >> 6, lane = tid & 63;
    const int lr = lane & 15, lg = lane >> 4;
    const int wr = wave >> 2, wc = wave & 3;
    const int work = (blockIdx.x & 7) * 64 + (blockIdx.x >> 3);
    const int rb = work >> 2, cb = work & 3;
    const int t0 = rb * 256, c0 = cb * 256;

    float4v acc[8][4];
    #pragma unroll
    for (int i = 0; i < 8; ++i)
        #pragma unroll
        for (int j = 0; j < 4; ++j)
            acc[i][j] = (float4v){0.f, 0.f, 0.f, 0.f};

    // half-tile h: tile T=h>>2, j=h&3 (0=A-k0, 1=B-k0, 2=A-k1, 3=B-k1)
    auto stageHalf = [&](int h) {
        if (h >= 32) return;
        int T = h >> 2, j = h & 3;
        int khalf = j >> 1, isB = j & 1;
        const unsigned short* plane = isB ? Xhi : Ehi;
        int row0 = isB ? t0 : c0;
        int kseg = T * 64 + khalf * 32;
        char* region = smem + (T & 1) * 65536 + isB * 32768 + khalf * 16384;
        #pragma unroll
        for (int jj = 0; jj < 2; ++jj) {
            int o = jj * 8192 + wave * 1024 + lane * 16;
            int pair = o >> 7;
            int sl = ((o >> 4) & 7) ^ (pair & 7);
            int row = pair * 2 + (sl >> 2);
            int k8 = sl & 3;
            GLOAD_LDS16(plane + (size_t)(row0 + row) * D_ + kseg + k8 * 8,
                        region + jj * 8192 + wave * 1024);
        }
    };

    for (int h = 0; h < 6; ++h) stageHalf(h);

    for (int t = 0; t < 8; ++t) {
        const int buf = t & 1;
        const char* Ab = smem + buf * 65536;
        const char* Bb = smem + buf * 65536 + 32768;
        if (t < 7) { asm volatile("s_waitcnt vmcnt(4)" ::: "memory"); }
        else       { asm volatile("s_waitcnt vmcnt(0)" ::: "memory"); }
        __builtin_amdgcn_s_barrier();
        __builtin_amdgcn_sched_barrier(0);
        #pragma unroll
        for (int q = 0; q < 4; ++q) {
            const int ks = q >> 1, mq = q & 1;
            const char* Ar = Ab + ks * 16384;
            const char* Br = Bb + ks * 16384;
            short8 af[4], bf[4];
            #pragma unroll
            for (int i = 0; i < 4; ++i) {
                int arow = wr * 128 + (mq * 4 + i) * 16 + lr;
                int ap = arow >> 1;
                int as_ = (((arow & 1) << 2) | lg) ^ (ap & 7);
                af[i] = *(const short8*)(Ar + ap * 128 + as_ * 16);
            }
            #pragma unroll
            for (int i = 0; i < 4; ++i) {
                int brow = wc * 64 + i * 16 + lr;
                int bp = brow >> 1;
                int bs_ = (((brow & 1) << 2) | lg) ^ (bp & 7);
                bf[i] = *(const short8*)(Br + bp * 128 + bs_ * 16);
            }
            stageHalf(4 * t + q + 6);
            __builtin_amdgcn_sched_barrier(0);
            __builtin_amdgcn_s_barrier();
            asm volatile("s_waitcnt lgkmcnt(0)" ::: "memory");
            __builtin_amdgcn_sched_barrier(0);
            __builtin_amdgcn_s_setprio(1);
            #pragma unroll
            for (int i = 0; i < 4; ++i)
                #pragma unroll
                for (int j = 0; j < 4; ++j)
                    acc[mq * 4 + i][j] = __builtin_amdgcn_mfma_f32_16x16x32_bf16(af[i], bf[j], acc[mq * 4 + i][j], 0, 0, 0);
            __builtin_amdgcn_s_setprio(0);
            __builtin_amdgcn_s_barrier();
        }
    }

    float en[8][4];
    #pragma unroll
    for (int mi = 0; mi < 8; ++mi)
        #pragma unroll
        for (int rr = 0; rr < 4; ++rr)
            en[mi][rr] = enorm[c0 + wr * 128 + mi * 16 + lg * 4 + rr];

    #pragma unroll
    for (int ni = 0; ni < 4; ++ni) {
        float v1 = 3.4e38f, v2 = 3.4e38f;
        int c1 = 0;
        #pragma unroll
        for (int mi = 0; mi < 8; ++mi) {
            #pragma unroll
            for (int rr = 0; rr < 4; ++rr) {
                float dist = fmaf(-2.f, acc[mi][ni][rr], en[mi][rr]);
                int code = c0 + wr * 128 + mi * 16 + lg * 4 + rr;
                if (dist < v1) { v2 = v1; v1 = dist; c1 = code; }
                else v2 = fminf(v2, dist);
            }
        }
        #pragma unroll
        for (int mask = 16; mask <= 32; mask <<= 1) {
            float ov1 = __shfl_xor(v1, mask, 64);
            int   oc1 = __shfl_xor(c1, mask, 64);
            float ov2 = __shfl_xor(v2, mask, 64);
            bool take = (ov1 < v1) || (ov1 == v1 && oc1 < c1);
            float loser = take ? v1 : ov1;
            v2 = fminf(fminf(v2, ov2), loser);
            if (take) { v1 = ov1; c1 = oc1; }
        }
        if (lg == 0) {
            int t = t0 + wc * 64 + ni * 16 + lr;
            ulonglong2 pk;
            pk.x = ((u64)fkey(v1) << 32) | (unsigned)c1;
            pk.y = ((u64)fkey(v2) << 32);
            *(ulonglong2*)&part[((size_t)t * 8 + cb * 2 + wr) * 2] = pk;
        }
    }
}

// ------------------------------------------------------------- k_merge
__global__ __launch_bounds__(256) void k_merge(const u64* __restrict__ part,
                                               int* __restrict__ indices,
                                               int* __restrict__ flags,
                                               int* __restrict__ flagCount) {
    int t = blockIdx.x * 256 + threadIdx.x;
    ulonglong2 a0 = *(const ulonglong2*)&part[(size_t)t * 16];
    u64 m1 = a0.x;
    float m2v = funkey((unsigned)(a0.y >> 32));
    for (int s = 1; s < 8; ++s) {
        ulonglong2 a = *(const ulonglong2*)&part[((size_t)t * 8 + s) * 2];
        float ax = funkey((unsigned)(a.x >> 32));
        float ay = funkey((unsigned)(a.y >> 32));
        if (a.x < m1) { m2v = fminf(m2v, funkey((unsigned)(m1 >> 32))); m1 = a.x; }
        else m2v = fminf(m2v, ax);
        m2v = fminf(m2v, ay);
    }
    indices[t] = (int)(m1 & 0xffffffffu);
    float v1 = funkey((unsigned)(m1 >> 32));
    if (m2v - v1 < GAP_THR) {
        int pos = atomicAdd(flagCount, 1);
        if (pos < N_) flags[pos] = t;
    }
}

// ------------------------------------------------------------- k_repair
// fp64 exact re-argmin for flagged tokens. Lane-per-code with transposed
// codebook ET[512][1024]; 4 tokens per block amortize ET traffic.
__global__ __launch_bounds__(256) void k_repair(const float* __restrict__ z,
                                                const float* __restrict__ ET,
                                                const double* __restrict__ enormD,
                                                const int* __restrict__ flags,
                                                const int* __restrict__ flagCount,
                                                int* __restrict__ indices) {
    __shared__ double zl[4][512];   // 16 KB
    __shared__ double rv[256];
    __shared__ int rc[256];
    const int tid = threadIdx.x;
    int nf = *flagCount;
    if (nf > N_) nf = N_;
    int nb = (nf + 3) >> 2;
    for (int bi = blockIdx.x; bi < nb; bi += gridDim.x) {
        int base = bi * 4;
        int ntok = nf - base; if (ntok > 4) ntok = 4;
        __syncthreads();   // protect zl reuse across grid-stride iterations
        for (int i = tid; i < 2048; i += 256) {
            int g = i >> 9, d = i & 511;
            if (g < ntok) {
                int t = flags[base + g];
                zl[g][d] = (double)z[(size_t)(t >> 10) * (D_ * P_) + (size_t)d * P_ + (t & 1023)];
            } else {
                zl[g][d] = 0.0;
            }
        }
        __syncthreads();

        double acc[4][4];
        #pragma unroll
        for (int g = 0; g < 4; ++g)
            #pragma unroll
            for (int k = 0; k < 4; ++k) acc[g][k] = 0.0;

        #pragma unroll 4
        for (int d = 0; d < 512; ++d) {
            const float* ep = ET + (size_t)d * 1024 + tid;
            double e0 = (double)ep[0];
            double e1 = (double)ep[256];
            double e2 = (double)ep[512];
            double e3 = (double)ep[768];
            double z0 = zl[0][d], z1 = zl[1][d], z2 = zl[2][d], z3 = zl[3][d];
            acc[0][0] = fma(e0, z0, acc[0][0]);
            acc[0][1] = fma(e1, z0, acc[0][1]);
            acc[0][2] = fma(e2, z0, acc[0][2]);
            acc[0][3] = fma(e3, z0, acc[0][3]);
            acc[1][0] = fma(e0, z1, acc[1][0]);
            acc[1][1] = fma(e1, z1, acc[1][1]);
            acc[1][2] = fma(e2, z1, acc[1][2]);
            acc[1][3] = fma(e3, z1, acc[1][3]);
            acc[2][0] = fma(e0, z2, acc[2][0]);
            acc[2][1] = fma(e1, z2, acc[2][1]);
            acc[2][2] = fma(e2, z2, acc[2][2]);
            acc[2][3] = fma(e3, z2, acc[2][3]);
            acc[3][0] = fma(e0, z3, acc[3][0]);
            acc[3][1] = fma(e1, z3, acc[3][1]);
            acc[3][2] = fma(e2, z3, acc[3][2]);
            acc[3][3] = fma(e3, z3, acc[3][3]);
        }

        for (int g = 0; g < ntok; ++g) {
            double bv = 1e300;
            int bc = 0;
            #pragma unroll
            for (int k = 0; k < 4; ++k) {
                int c = k * 256 + tid;   // ascending c: strict < keeps lowest on tie
                double dist = enormD[c] - 2.0 * acc[g][k];
                if (dist < bv) { bv = dist; bc = c; }
            }
            rv[tid] = bv; rc[tid] = bc;
            __syncthreads();
            for (int st = 128; st; st >>= 1) {
                if (tid < st) {
                    if (rv[tid + st] < rv[tid] ||
                        (rv[tid + st] == rv[tid] && rc[tid + st] < rc[tid])) {
                        rv[tid] = rv[tid + st]; rc[tid] = rc[tid + st];
                    }
                }
                __syncthreads();
            }
            if (tid == 0) indices[flags[base + g]] = rc[0];
            __syncthreads();
        }
    }
}

// ------------------------------------------------------------- k_out
// (r8-exact gather structure; one-hot zeros now done by hipMemsetAsync).
// 256 blocks x 128 tokens x 512 dims: LDS-staged emb rows, coalesced z read,
// z_q write, loss partials. First 128 threads also scatter the 1.0f one-hot
// entries + counts (enc was memset to zero just before this kernel).
__global__ __launch_bounds__(256) void k_out(const int* __restrict__ indices,
                                             float* __restrict__ enc,
                                             int* __restrict__ counts,
                                             const float* __restrict__ z,
                                             const float* __restrict__ emb,
                                             float* __restrict__ zq,
                                             float* __restrict__ lossp) {
    __shared__ int sIdx[128];
    __shared__ float El[128 * 65];   // [token][dim-in-chunk], pad 65
    int tid = threadIdx.x;
    int gb = blockIdx.x;
    int b = gb >> 3, pt = gb & 7;
    int p0 = pt * 128;
    if (tid < 128) {
        int t = b * P_ + p0 + tid;
        int idx = indices[t];
        sIdx[tid] = idx;
        enc[(size_t)t * K_ + idx] = 1.0f;
        atomicAdd(&counts[idx], 1);
    }
    __syncthreads();

    float lsum = 0.f;
    for (int dc = 0; dc < 8; ++dc) {
        int d0 = dc * 64;
        // stage emb rows: 4 passes x 32 tokens; 8 lanes x 2 float4 per token
        #pragma unroll
        for (int pass = 0; pass < 4; ++pass) {
            int p = pass * 32 + (tid >> 3);
            int l8 = tid & 7;
            const float* er = emb + (size_t)sIdx[p] * D_ + d0 + l8 * 8;
            float4 e0 = *(const float4*)er;
            float4 e1 = *(const float4*)(er + 4);
            int base = p * 65 + l8 * 8;
            El[base + 0] = e0.x; El[base + 1] = e0.y;
            El[base + 2] = e0.z; El[base + 3] = e0.w;
            El[base + 4] = e1.x; El[base + 5] = e1.y;
            El[base + 6] = e1.z; El[base + 7] = e1.w;
        }
        __syncthreads();
        #pragma unroll
        for (int it = 0; it < 8; ++it) {
            int f = it * 256 + tid;
            int d = f >> 5, p4 = f & 31;
            size_t zoff = (size_t)b * (D_ * P_) + (size_t)(d0 + d) * P_ + p0 + p4 * 4;
            float4 zv = *(const float4*)(z + zoff);
            float e0 = El[(p4 * 4 + 0) * 65 + d];
            float e1 = El[(p4 * 4 + 1) * 65 + d];
            float e2 = El[(p4 * 4 + 2) * 65 + d];
            float e3 = El[(p4 * 4 + 3) * 65 + d];
            float q0 = e0 - zv.x, q1 = e1 - zv.y, q2 = e2 - zv.z, q3 = e3 - zv.w;
            float4 o;
            o.x = zv.x + q0; o.y = zv.y + q1; o.z = zv.z + q2; o.w = zv.w + q3;
            *(float4*)(zq + zoff) = o;
            lsum += q0 * q0 + q1 * q1 + q2 * q2 + q3 * q3;
        }
        __syncthreads();
    }
    #pragma unroll
    for (int off = 32; off; off >>= 1) lsum += __shfl_down(lsum, off, 64);
    __shared__ float wsum[4];
    if ((tid & 63) == 0) wsum[tid >> 6] = lsum;
    __syncthreads();
    if (tid == 0) lossp[gb] = wsum[0] + wsum[1] + wsum[2] + wsum[3];
}

// ------------------------------------------------------------- k_final
__global__ __launch_bounds__(1024) void k_final(const float* __restrict__ lossp,
                                                const int* __restrict__ counts,
                                                float* __restrict__ out_loss,
                                                float* __restrict__ out_perp) {
    int tid = threadIdx.x;
    float s = (tid < 256) ? lossp[tid] : 0.f;
    #pragma unroll
    for (int off = 32; off; off >>= 1) s += __shfl_down(s, off, 64);
    __shared__ float red[16];
    if ((tid & 63) == 0) red[tid >> 6] = s;

    float pr = (float)counts[tid] * (1.f / 32768.f);
    float term = pr * logf(pr + 1e-10f);
    #pragma unroll
    for (int off = 32; off; off >>= 1) term += __shfl_down(term, off, 64);
    __shared__ float red2[16];
    if ((tid & 63) == 0) red2[tid >> 6] = term;
    __syncthreads();
    if (tid == 0) {
        float tot = 0.f;
        for (int i = 0; i < 16; ++i) tot += red[i];
        *out_loss = 0.25f * (tot / 16777216.f);
        float t2 = 0.f;
        for (int i = 0; i < 16; ++i) t2 += red2[i];
        *out_perp = expf(-t2);
    }
}

// ------------------------------------------------------------- launch
extern "C" void kernel_launch(void* const* d_in, const int* in_sizes, int n_in,
                              void* d_out, int out_size, void* d_ws, size_t ws_size,
                              hipStream_t stream) {
    const float* z   = (const float*)d_in[0];   // [32,512,32,32]
    const float* emb = (const float*)d_in[1];   // [1024,512]

    float* zq       = (float*)d_out;            // 16777216
    float* out_loss = zq + 16777216;
    float* out_perp = zq + 16777217;
    float* enc      = zq + 16777218;            // 33554432 floats

    char* ws = (char*)d_ws;
    float* enorm   = (float*)ws;                          // 4 KB
    int* counts    = (int*)(ws + 4096);                   // 4 KB
    int* flagCount = (int*)(ws + 8192);                   // 4 B
    double* enormD = (double*)(ws + 16384);               // 8 KB
    int* flags     = (int*)(ws + 24576);                  // 128 KB
    int* indices   = (int*)(ws + 24576 + 131072);         // 128 KB
    float* lossp   = (float*)(ws + 24576 + 262144);       // 1 KB used

    // big scratch carved from the enc region of d_out (fully consumed before
    // the enc memset wipes it; rewritten every call -> deterministic).
    char* sb = (char*)d_out + 67108880;
    unsigned short* Xhi  = (unsigned short*)(sb);                   // 33.5 MB
    unsigned short* EhiP = (unsigned short*)(sb + 33554432);        // 1 MB
    u64* part = (u64*)(sb + 34603008);                              // 4 MB
    float* ET = (float*)(sb + 38797312);                            // 2 MB

    k_prep<<<384, 256, 0, stream>>>(z, Xhi, emb, EhiP, ET, enorm, enormD, counts, flagCount);
    k_gemm<<<512, 512, 0, stream>>>(Xhi, EhiP, enorm, part);
    k_merge<<<128, 256, 0, stream>>>(part, indices, flags, flagCount);
    k_repair<<<512, 256, 0, stream>>>(z, ET, enormD, flags, flagCount, indices);
    // zero the one-hot matrix at memset BW (~7 TB/s); scratch above is dead now.
    hipMemsetAsync(enc, 0, (size_t)33554432 * 4, stream);
    k_out<<<256, 256, 0, stream>>>(indices, enc, counts, z, emb, zq, lossp);
    k_final<<<1, 1024, 0, stream>>>(lossp, counts, out_loss, out_perp);
}

// Round 11
// 209.907 us; speedup vs baseline: 1.0784x; 1.0320x over previous
//
#include <hip/hip_runtime.h>
#include <stdint.h>

#define B_ 32
#define D_ 512
#define P_ 1024   // H*W
#define N_ 32768  // B*P
#define K_ 1024

// 1-segment (bf16-hi only) distance error: sigma ~0.07/dist, gap sigma ~0.1.
// 0.75 = 7.5 sigma guard; measured flag rate ~3-5% of tokens -> fp64 repair.
#define GAP_THR 0.75f

typedef unsigned long long u64;
typedef __attribute__((ext_vector_type(8))) short short8;
typedef __attribute__((ext_vector_type(4))) float float4v;

__device__ __forceinline__ unsigned fkey(float f) {
    unsigned u = __float_as_uint(f);
    return (u & 0x80000000u) ? ~u : (u | 0x80000000u);
}
__device__ __forceinline__ float funkey(unsigned k) {
    unsigned u = (k & 0x80000000u) ? (k & 0x7fffffffu) : ~k;
    return __uint_as_float(u);
}
__device__ __forceinline__ unsigned short f2bf(float x) {
    unsigned u = __float_as_uint(x);
    unsigned r = (u + 0x7fffu + ((u >> 16) & 1u)) >> 16;
    return (unsigned short)r;
}
__device__ __forceinline__ float bf2f(unsigned short h) {
    return __uint_as_float(((unsigned)h) << 16);
}

#define GLOAD_LDS16(gsrc, ldst) \
    __builtin_amdgcn_global_load_lds((const __attribute__((address_space(1))) unsigned int*)(const void*)(gsrc), \
                                     (__attribute__((address_space(3))) unsigned int*)(void*)(ldst), 16, 0, 0)

// ------------------------------------------------------------- k_prep
// blocks 0..255: z [32,512,1024] fp32 -> Xhi bf16 [32768][512] (LDS transpose)
// blocks 256..383: emb -> Ehi bf16 + ET fp32 [512][1024] + enorm(f32)/enormD(f64);
//                  zero counts/flagCount
__global__ __launch_bounds__(256) void k_prep(const float* __restrict__ z,
                                              unsigned short* __restrict__ Xhi,
                                              const float* __restrict__ emb,
                                              unsigned short* __restrict__ Ehi,
                                              float* __restrict__ ET,
                                              float* __restrict__ enorm,
                                              double* __restrict__ enormD,
                                              int* __restrict__ counts,
                                              int* __restrict__ flagCount) {
    __shared__ float Zl[128][67];   // 34.3 KB; prepE aliases first 8*513 floats
    int tid = threadIdx.x;

    if (blockIdx.x >= 256) {
        // ---- prepE: 128 blocks x 8 codes (wave w handles 2 codes)
        int base = (blockIdx.x - 256) * 8;
        if (tid < 8) counts[base + tid] = 0;
        if (blockIdx.x == 256 && tid == 0) *flagCount = 0;
        int wave = tid >> 6, lane = tid & 63;
        float* Es = &Zl[0][0];      // [8][513]
        #pragma unroll
        for (int cc = 0; cc < 2; ++cc) {
            int ci = wave * 2 + cc;
            int c = base + ci;
            const float4* row = (const float4*)(emb + (size_t)c * D_);
            float4 a = row[lane * 2];
            float4 b2 = row[lane * 2 + 1];
            float xs[8] = {a.x, a.y, a.z, a.w, b2.x, b2.y, b2.z, b2.w};
            unsigned short h[8];
            double s = 0.0;
            #pragma unroll
            for (int j = 0; j < 8; ++j) {
                h[j] = f2bf(xs[j]);
                Es[ci * 513 + lane * 8 + j] = xs[j];
                double d = (double)xs[j];
                s += d * d;
            }
            uint4 w;
            w.x = (unsigned)h[0] | ((unsigned)h[1] << 16);
            w.y = (unsigned)h[2] | ((unsigned)h[3] << 16);
            w.z = (unsigned)h[4] | ((unsigned)h[5] << 16);
            w.w = (unsigned)h[6] | ((unsigned)h[7] << 16);
            *(uint4*)(Ehi + (size_t)c * D_ + lane * 8) = w;
            #pragma unroll
            for (int off = 32; off; off >>= 1) s += __shfl_down(s, off, 64);
            if (lane == 0) { enorm[c] = (float)s; enormD[c] = s; }
        }
        __syncthreads();
        // transpose write: thread handles d = tid, tid+256 -> ET[d][base..base+7]
        #pragma unroll
        for (int g = 0; g < 2; ++g) {
            int d = g * 256 + tid;
            float v[8];
            #pragma unroll
            for (int cc = 0; cc < 8; ++cc) v[cc] = Es[cc * 513 + d];
            float4* dst = (float4*)(ET + (size_t)d * 1024 + base);
            dst[0] = make_float4(v[0], v[1], v[2], v[3]);
            dst[1] = make_float4(v[4], v[5], v[6], v[7]);
        }
        return;
    }

    // ---- prep: 128 tokens x 512 dims per block
    int b = blockIdx.x >> 3, pt = blockIdx.x & 7;
    int p0 = pt * 128;
    int t0 = b * P_ + p0;
    const float* zb = z + ((size_t)b * D_) * P_ + p0;
    int c8 = tid & 7, pp = tid >> 3;

    for (int dc = 0; dc < 8; ++dc) {
        int d0 = dc * 64;
        __syncthreads();
        #pragma unroll
        for (int jj = 0; jj < 8; ++jj) {
            int flat = jj * 256 + tid;
            int d = flat >> 5, p4 = flat & 31;
            float4 v = *(const float4*)(zb + (size_t)(d0 + d) * P_ + p4 * 4);
            Zl[p4 * 4 + 0][d] = v.x;
            Zl[p4 * 4 + 1][d] = v.y;
            Zl[p4 * 4 + 2][d] = v.z;
            Zl[p4 * 4 + 3][d] = v.w;
        }
        __syncthreads();
        #pragma unroll
        for (int g = 0; g < 4; ++g) {
            int p = pp + g * 32;
            unsigned short hh[8];
            #pragma unroll
            for (int j = 0; j < 8; ++j) hh[j] = f2bf(Zl[p][c8 * 8 + j]);
            uint4 w;
            w.x = (unsigned)hh[0] | ((unsigned)hh[1] << 16);
            w.y = (unsigned)hh[2] | ((unsigned)hh[3] << 16);
            w.z = (unsigned)hh[4] | ((unsigned)hh[5] << 16);
            w.w = (unsigned)hh[6] | ((unsigned)hh[7] << 16);
            *(uint4*)(Xhi + (size_t)(t0 + p) * D_ + d0 + c8 * 8) = w;
        }
    }
}

// ------------------------------------------------------------- k_gemm
// 256x256 tile, BK=64, 8 waves, 8-phase schedule, counted vmcnt, setprio.
// A = codes (Ehi), B = tokens (Xhi). K' = 512 = 8 tiles.
__global__ __launch_bounds__(512, 2) void k_gemm(const unsigned short* __restrict__ Xhi,
                                                 const unsigned short* __restrict__ Ehi,
                                                 const float* __restrict__ enorm,
                                                 u64* __restrict__ part) {
    __shared__ __align__(16) char smem[131072];
    const int tid = threadIdx.x;
    const int wave = tid >> 6, lane = tid & 63;
    const int lr = lane & 15, lg = lane >> 4;
    const int wr = wave >> 2, wc = wave & 3;
    const int work = (blockIdx.x & 7) * 64 + (blockIdx.x >> 3);
    const int rb = work >> 2, cb = work & 3;
    const int t0 = rb * 256, c0 = cb * 256;

    float4v acc[8][4];
    #pragma unroll
    for (int i = 0; i < 8; ++i)
        #pragma unroll
        for (int j = 0; j < 4; ++j)
            acc[i][j] = (float4v){0.f, 0.f, 0.f, 0.f};

    // half-tile h: tile T=h>>2, j=h&3 (0=A-k0, 1=B-k0, 2=A-k1, 3=B-k1)
    auto stageHalf = [&](int h) {
        if (h >= 32) return;
        int T = h >> 2, j = h & 3;
        int khalf = j >> 1, isB = j & 1;
        const unsigned short* plane = isB ? Xhi : Ehi;
        int row0 = isB ? t0 : c0;
        int kseg = T * 64 + khalf * 32;
        char* region = smem + (T & 1) * 65536 + isB * 32768 + khalf * 16384;
        #pragma unroll
        for (int jj = 0; jj < 2; ++jj) {
            int o = jj * 8192 + wave * 1024 + lane * 16;
            int pair = o >> 7;
            int sl = ((o >> 4) & 7) ^ (pair & 7);
            int row = pair * 2 + (sl >> 2);
            int k8 = sl & 3;
            GLOAD_LDS16(plane + (size_t)(row0 + row) * D_ + kseg + k8 * 8,
                        region + jj * 8192 + wave * 1024);
        }
    };

    for (int h = 0; h < 6; ++h) stageHalf(h);

    for (int t = 0; t < 8; ++t) {
        const int buf = t & 1;
        const char* Ab = smem + buf * 65536;
        const char* Bb = smem + buf * 65536 + 32768;
        if (t < 7) { asm volatile("s_waitcnt vmcnt(4)" ::: "memory"); }
        else       { asm volatile("s_waitcnt vmcnt(0)" ::: "memory"); }
        __builtin_amdgcn_s_barrier();
        __builtin_amdgcn_sched_barrier(0);
        #pragma unroll
        for (int q = 0; q < 4; ++q) {
            const int ks = q >> 1, mq = q & 1;
            const char* Ar = Ab + ks * 16384;
            const char* Br = Bb + ks * 16384;
            short8 af[4], bf[4];
            #pragma unroll
            for (int i = 0; i < 4; ++i) {
                int arow = wr * 128 + (mq * 4 + i) * 16 + lr;
                int ap = arow >> 1;
                int as_ = (((arow & 1) << 2) | lg) ^ (ap & 7);
                af[i] = *(const short8*)(Ar + ap * 128 + as_ * 16);
            }
            #pragma unroll
            for (int i = 0; i < 4; ++i) {
                int brow = wc * 64 + i * 16 + lr;
                int bp = brow >> 1;
                int bs_ = (((brow & 1) << 2) | lg) ^ (bp & 7);
                bf[i] = *(const short8*)(Br + bp * 128 + bs_ * 16);
            }
            stageHalf(4 * t + q + 6);
            __builtin_amdgcn_sched_barrier(0);
            __builtin_amdgcn_s_barrier();
            asm volatile("s_waitcnt lgkmcnt(0)" ::: "memory");
            __builtin_amdgcn_sched_barrier(0);
            __builtin_amdgcn_s_setprio(1);
            #pragma unroll
            for (int i = 0; i < 4; ++i)
                #pragma unroll
                for (int j = 0; j < 4; ++j)
                    acc[mq * 4 + i][j] = __builtin_amdgcn_mfma_f32_16x16x32_bf16(af[i], bf[j], acc[mq * 4 + i][j], 0, 0, 0);
            __builtin_amdgcn_s_setprio(0);
            __builtin_amdgcn_s_barrier();
        }
    }

    float en[8][4];
    #pragma unroll
    for (int mi = 0; mi < 8; ++mi)
        #pragma unroll
        for (int rr = 0; rr < 4; ++rr)
            en[mi][rr] = enorm[c0 + wr * 128 + mi * 16 + lg * 4 + rr];

    #pragma unroll
    for (int ni = 0; ni < 4; ++ni) {
        float v1 = 3.4e38f, v2 = 3.4e38f;
        int c1 = 0;
        #pragma unroll
        for (int mi = 0; mi < 8; ++mi) {
            #pragma unroll
            for (int rr = 0; rr < 4; ++rr) {
                float dist = fmaf(-2.f, acc[mi][ni][rr], en[mi][rr]);
                int code = c0 + wr * 128 + mi * 16 + lg * 4 + rr;
                if (dist < v1) { v2 = v1; v1 = dist; c1 = code; }
                else v2 = fminf(v2, dist);
            }
        }
        #pragma unroll
        for (int mask = 16; mask <= 32; mask <<= 1) {
            float ov1 = __shfl_xor(v1, mask, 64);
            int   oc1 = __shfl_xor(c1, mask, 64);
            float ov2 = __shfl_xor(v2, mask, 64);
            bool take = (ov1 < v1) || (ov1 == v1 && oc1 < c1);
            float loser = take ? v1 : ov1;
            v2 = fminf(fminf(v2, ov2), loser);
            if (take) { v1 = ov1; c1 = oc1; }
        }
        if (lg == 0) {
            int t = t0 + wc * 64 + ni * 16 + lr;
            ulonglong2 pk;
            pk.x = ((u64)fkey(v1) << 32) | (unsigned)c1;
            pk.y = ((u64)fkey(v2) << 32);
            *(ulonglong2*)&part[((size_t)t * 8 + cb * 2 + wr) * 2] = pk;
        }
    }
}

// ------------------------------------------------------------- k_merge
__global__ __launch_bounds__(256) void k_merge(const u64* __restrict__ part,
                                               int* __restrict__ indices,
                                               int* __restrict__ flags,
                                               int* __restrict__ flagCount) {
    int t = blockIdx.x * 256 + threadIdx.x;
    ulonglong2 a0 = *(const ulonglong2*)&part[(size_t)t * 16];
    u64 m1 = a0.x;
    float m2v = funkey((unsigned)(a0.y >> 32));
    for (int s = 1; s < 8; ++s) {
        ulonglong2 a = *(const ulonglong2*)&part[((size_t)t * 8 + s) * 2];
        float ax = funkey((unsigned)(a.x >> 32));
        float ay = funkey((unsigned)(a.y >> 32));
        if (a.x < m1) { m2v = fminf(m2v, funkey((unsigned)(m1 >> 32))); m1 = a.x; }
        else m2v = fminf(m2v, ax);
        m2v = fminf(m2v, ay);
    }
    indices[t] = (int)(m1 & 0xffffffffu);
    float v1 = funkey((unsigned)(m1 >> 32));
    if (m2v - v1 < GAP_THR) {
        int pos = atomicAdd(flagCount, 1);
        if (pos < N_) flags[pos] = t;
    }
}

// ------------------------------------------------------------- k_repair
// fp64 exact re-argmin for flagged tokens. Lane-per-code with transposed
// codebook ET[512][1024]; 4 tokens per block amortize ET traffic.
__global__ __launch_bounds__(256) void k_repair(const float* __restrict__ z,
                                                const float* __restrict__ ET,
                                                const double* __restrict__ enormD,
                                                const int* __restrict__ flags,
                                                const int* __restrict__ flagCount,
                                                int* __restrict__ indices) {
    __shared__ double zl[4][512];   // 16 KB
    __shared__ double rv[256];
    __shared__ int rc[256];
    const int tid = threadIdx.x;
    int nf = *flagCount;
    if (nf > N_) nf = N_;
    int nb = (nf + 3) >> 2;
    for (int bi = blockIdx.x; bi < nb; bi += gridDim.x) {
        int base = bi * 4;
        int ntok = nf - base; if (ntok > 4) ntok = 4;
        __syncthreads();   // protect zl reuse across grid-stride iterations
        for (int i = tid; i < 2048; i += 256) {
            int g = i >> 9, d = i & 511;
            if (g < ntok) {
                int t = flags[base + g];
                zl[g][d] = (double)z[(size_t)(t >> 10) * (D_ * P_) + (size_t)d * P_ + (t & 1023)];
            } else {
                zl[g][d] = 0.0;
            }
        }
        __syncthreads();

        double acc[4][4];
        #pragma unroll
        for (int g = 0; g < 4; ++g)
            #pragma unroll
            for (int k = 0; k < 4; ++k) acc[g][k] = 0.0;

        #pragma unroll 4
        for (int d = 0; d < 512; ++d) {
            const float* ep = ET + (size_t)d * 1024 + tid;
            double e0 = (double)ep[0];
            double e1 = (double)ep[256];
            double e2 = (double)ep[512];
            double e3 = (double)ep[768];
            double z0 = zl[0][d], z1 = zl[1][d], z2 = zl[2][d], z3 = zl[3][d];
            acc[0][0] = fma(e0, z0, acc[0][0]);
            acc[0][1] = fma(e1, z0, acc[0][1]);
            acc[0][2] = fma(e2, z0, acc[0][2]);
            acc[0][3] = fma(e3, z0, acc[0][3]);
            acc[1][0] = fma(e0, z1, acc[1][0]);
            acc[1][1] = fma(e1, z1, acc[1][1]);
            acc[1][2] = fma(e2, z1, acc[1][2]);
            acc[1][3] = fma(e3, z1, acc[1][3]);
            acc[2][0] = fma(e0, z2, acc[2][0]);
            acc[2][1] = fma(e1, z2, acc[2][1]);
            acc[2][2] = fma(e2, z2, acc[2][2]);
            acc[2][3] = fma(e3, z2, acc[2][3]);
            acc[3][0] = fma(e0, z3, acc[3][0]);
            acc[3][1] = fma(e1, z3, acc[3][1]);
            acc[3][2] = fma(e2, z3, acc[3][2]);
            acc[3][3] = fma(e3, z3, acc[3][3]);
        }

        for (int g = 0; g < ntok; ++g) {
            double bv = 1e300;
            int bc = 0;
            #pragma unroll
            for (int k = 0; k < 4; ++k) {
                int c = k * 256 + tid;   // ascending c: strict < keeps lowest on tie
                double dist = enormD[c] - 2.0 * acc[g][k];
                if (dist < bv) { bv = dist; bc = c; }
            }
            rv[tid] = bv; rc[tid] = bc;
            __syncthreads();
            for (int st = 128; st; st >>= 1) {
                if (tid < st) {
                    if (rv[tid + st] < rv[tid] ||
                        (rv[tid + st] == rv[tid] && rc[tid + st] < rc[tid])) {
                        rv[tid] = rv[tid + st]; rc[tid] = rc[tid + st];
                    }
                }
                __syncthreads();
            }
            if (tid == 0) indices[flags[base + g]] = rc[0];
            __syncthreads();
        }
    }
}

// ------------------------------------------------------------- k_out
// blocks 0..4095: one-hot encodings + counts (coalesced streaming writes).
// blocks 4096..4351: z_q gather via LDS-staged emb rows -- token-parallel
// coalesced gather, then writer threads read z as float4 (coalesced),
// compute o = z + (e-z), write zq coalesced, accumulate loss.
__global__ __launch_bounds__(256) void k_out(const int* __restrict__ indices,
                                             float* __restrict__ enc,
                                             int* __restrict__ counts,
                                             const float* __restrict__ z,
                                             const float* __restrict__ emb,
                                             float* __restrict__ zq,
                                             float* __restrict__ lossp) {
    int tid = threadIdx.x;
    if (blockIdx.x < 4096) {
        int r = blockIdx.x * 8 + (tid >> 5);
        int l = tid & 31;
        int idx = indices[r];
        if (l == 0) atomicAdd(&counts[idx], 1);
        float4* rowp = (float4*)(enc + (size_t)r * K_);
        #pragma unroll
        for (int i = 0; i < 8; ++i) {
            int c4 = i * 32 + l;
            int base = c4 * 4;
            float4 v;
            v.x = (idx == base) ? 1.f : 0.f;
            v.y = (idx == base + 1) ? 1.f : 0.f;
            v.z = (idx == base + 2) ? 1.f : 0.f;
            v.w = (idx == base + 3) ? 1.f : 0.f;
            rowp[c4] = v;
        }
        return;
    }

    // ---- gather half: 256 blocks, each 128 tokens x 512 dims
    __shared__ int sIdx[128];
    __shared__ float El[128 * 65];   // [token][dim-in-chunk], pad 65
    int gb = blockIdx.x - 4096;
    int b = gb >> 3, pt = gb & 7;
    int p0 = pt * 128;
    if (tid < 128) sIdx[tid] = indices[b * P_ + p0 + tid];
    __syncthreads();

    float lsum = 0.f;
    for (int dc = 0; dc < 8; ++dc) {
        int d0 = dc * 64;
        // stage emb rows: 4 passes x 32 tokens; 8 lanes x 2 float4 per token
        #pragma unroll
        for (int pass = 0; pass < 4; ++pass) {
            int p = pass * 32 + (tid >> 3);
            int l8 = tid & 7;
            const float* er = emb + (size_t)sIdx[p] * D_ + d0 + l8 * 8;
            float4 e0 = *(const float4*)er;
            float4 e1 = *(const float4*)(er + 4);
            int base = p * 65 + l8 * 8;
            El[base + 0] = e0.x; El[base + 1] = e0.y;
            El[base + 2] = e0.z; El[base + 3] = e0.w;
            El[base + 4] = e1.x; El[base + 5] = e1.y;
            El[base + 6] = e1.z; El[base + 7] = e1.w;
        }
        __syncthreads();
        #pragma unroll
        for (int it = 0; it < 8; ++it) {
            int f = it * 256 + tid;
            int d = f >> 5, p4 = f & 31;
            size_t zoff = (size_t)b * (D_ * P_) + (size_t)(d0 + d) * P_ + p0 + p4 * 4;
            float4 zv = *(const float4*)(z + zoff);
            float e0 = El[(p4 * 4 + 0) * 65 + d];
            float e1 = El[(p4 * 4 + 1) * 65 + d];
            float e2 = El[(p4 * 4 + 2) * 65 + d];
            float e3 = El[(p4 * 4 + 3) * 65 + d];
            float q0 = e0 - zv.x, q1 = e1 - zv.y, q2 = e2 - zv.z, q3 = e3 - zv.w;
            float4 o;
            o.x = zv.x + q0; o.y = zv.y + q1; o.z = zv.z + q2; o.w = zv.w + q3;
            *(float4*)(zq + zoff) = o;
            lsum += q0 * q0 + q1 * q1 + q2 * q2 + q3 * q3;
        }
        __syncthreads();
    }
    #pragma unroll
    for (int off = 32; off; off >>= 1) lsum += __shfl_down(lsum, off, 64);
    __shared__ float wsum[4];
    if ((tid & 63) == 0) wsum[tid >> 6] = lsum;
    __syncthreads();
    if (tid == 0) lossp[gb] = wsum[0] + wsum[1] + wsum[2] + wsum[3];
}

// ------------------------------------------------------------- k_final
__global__ __launch_bounds__(1024) void k_final(const float* __restrict__ lossp,
                                                const int* __restrict__ counts,
                                                float* __restrict__ out_loss,
                                                float* __restrict__ out_perp) {
    int tid = threadIdx.x;
    float s = (tid < 256) ? lossp[tid] : 0.f;
    #pragma unroll
    for (int off = 32; off; off >>= 1) s += __shfl_down(s, off, 64);
    __shared__ float red[16];
    if ((tid & 63) == 0) red[tid >> 6] = s;

    float pr = (float)counts[tid] * (1.f / 32768.f);
    float term = pr * logf(pr + 1e-10f);
    #pragma unroll
    for (int off = 32; off; off >>= 1) term += __shfl_down(term, off, 64);
    __shared__ float red2[16];
    if ((tid & 63) == 0) red2[tid >> 6] = term;
    __syncthreads();
    if (tid == 0) {
        float tot = 0.f;
        for (int i = 0; i < 16; ++i) tot += red[i];
        *out_loss = 0.25f * (tot / 16777216.f);
        float t2 = 0.f;
        for (int i = 0; i < 16; ++i) t2 += red2[i];
        *out_perp = expf(-t2);
    }
}

// ------------------------------------------------------------- launch
extern "C" void kernel_launch(void* const* d_in, const int* in_sizes, int n_in,
                              void* d_out, int out_size, void* d_ws, size_t ws_size,
                              hipStream_t stream) {
    const float* z   = (const float*)d_in[0];   // [32,512,32,32]
    const float* emb = (const float*)d_in[1];   // [1024,512]

    float* zq       = (float*)d_out;            // 16777216
    float* out_loss = zq + 16777216;
    float* out_perp = zq + 16777217;
    float* enc      = zq + 16777218;            // 33554432 floats

    char* ws = (char*)d_ws;
    float* enorm   = (float*)ws;                          // 4 KB
    int* counts    = (int*)(ws + 4096);                   // 4 KB
    int* flagCount = (int*)(ws + 8192);                   // 4 B
    double* enormD = (double*)(ws + 16384);               // 8 KB
    int* flags     = (int*)(ws + 24576);                  // 128 KB
    int* indices   = (int*)(ws + 24576 + 131072);         // 128 KB
    float* lossp   = (float*)(ws + 24576 + 262144);       // 1 KB used

    // big scratch carved from the enc region of d_out (fully consumed before
    // k_out overwrites it; rewritten every call -> deterministic).
    char* sb = (char*)d_out + 67108880;
    unsigned short* Xhi  = (unsigned short*)(sb);                   // 33.5 MB
    unsigned short* EhiP = (unsigned short*)(sb + 33554432);        // 1 MB
    u64* part = (u64*)(sb + 34603008);                              // 4 MB
    float* ET = (float*)(sb + 38797312);                            // 2 MB

    k_prep<<<384, 256, 0, stream>>>(z, Xhi, emb, EhiP, ET, enorm, enormD, counts, flagCount);
    k_gemm<<<512, 512, 0, stream>>>(Xhi, EhiP, enorm, part);
    k_merge<<<128, 256, 0, stream>>>(part, indices, flags, flagCount);
    k_repair<<<512, 256, 0, stream>>>(z, ET, enormD, flags, flagCount, indices);
    k_out<<<4352, 256, 0, stream>>>(indices, enc, counts, z, emb, zq, lossp);
    k_final<<<1, 1024, 0, stream>>>(lossp, counts, out_loss, out_perp);
}